// Round 12
// baseline (193.788 us; speedup 1.0000x reference)
//
#include <hip/hip_runtime.h>
#include <hip/hip_bf16.h>
#include <math.h>

typedef __bf16 bf16_t;
typedef __bf16 bf16x8 __attribute__((ext_vector_type(8)));
typedef __bf16 bf16x4 __attribute__((ext_vector_type(4)));
typedef __bf16 bf16x2 __attribute__((ext_vector_type(2)));
typedef float f32x4 __attribute__((ext_vector_type(4)));
typedef unsigned u32x4 __attribute__((ext_vector_type(4)));

// scale 1/sqrt(1024) folded with log2(e), plus half-ulp rounding bias
// (x * 2^0.0028169 = x * (1+2^-9)) so perm-truncation rounds on average.
#define SCALE_L2E 0.045084234f
#define ROUND_B 0.0028169f

#define MFMA16(a, b, c) __builtin_amdgcn_mfma_f32_16x16x32_bf16(a, b, c, 0, 0, 0)

// pack two f32 into bf16x2 (truncate): dst = (hi16(b) << 16) | hi16(a)
__device__ __forceinline__ unsigned pack2(float a, float b) {
  return __builtin_amdgcn_perm(__builtin_bit_cast(unsigned, b),
                               __builtin_bit_cast(unsigned, a), 0x07060302u);
}

// ---------------------------------------------------------------------------
// fused f32 -> bf16 convert of three buffers (x, w_qkv, w_o), 8 elems/thread
// ---------------------------------------------------------------------------
__global__ void convert3_f32_bf16(const float* __restrict__ a, int na,
                                  const float* __restrict__ b, int nb,
                                  const float* __restrict__ c, int nc,
                                  bf16_t* __restrict__ oa, bf16_t* __restrict__ ob,
                                  bf16_t* __restrict__ oc) {
  int i = (blockIdx.x * blockDim.x + threadIdx.x) * 8;
  const float* src;
  bf16_t* dst;
  int off;
  if (i < na) { src = a; dst = oa; off = i; }
  else if (i < na + nb) { src = b; dst = ob; off = i - na; }
  else if (i < na + nb + nc) { src = c; dst = oc; off = i - na - nb; }
  else return;
  float4 u = *(const float4*)&src[off];
  float4 v = *(const float4*)&src[off + 4];
  bf16x8 w = {(bf16_t)u.x, (bf16_t)u.y, (bf16_t)u.z, (bf16_t)u.w,
              (bf16_t)v.x, (bf16_t)v.y, (bf16_t)v.z, (bf16_t)v.w};
  *(bf16x8*)&dst[off] = w;
}

#define GLOBAL_AS __attribute__((address_space(1)))
#define LDS_AS __attribute__((address_space(3)))
__device__ __forceinline__ void g2l16(const void* g, void* l) {
  __builtin_amdgcn_global_load_lds((const GLOBAL_AS void*)g, (LDS_AS void*)l,
                                   16, 0, 0);
}

// ---------------------------------------------------------------------------
// 128x128 BT-GEMM, BK=32 double-buffer, ONE barrier per K-tile (R11, kept).
// 32 KiB LDS -> 4-5 blocks/CU co-resident; staging/read maps verbatim from
// the m97-style template that refcheck-passed R0-R4. R11 measured: total
// -3.5us vs the BK=64 2/CU variant (third confirmation that co-residency
// covers the per-tile vmcnt(0)+barrier drain).
// ---------------------------------------------------------------------------
__launch_bounds__(256, 4)
__global__ void gemm128k32(const bf16_t* __restrict__ A,
                           const bf16_t* __restrict__ B,
                           const float* __restrict__ bias,
                           bf16_t* __restrict__ C,
                           int M, int N, int K) {
  __shared__ __align__(16) bf16_t As[2][128 * 32];
  __shared__ __align__(16) bf16_t Bs[2][128 * 32];

  const int t = threadIdx.x;
  const int wave = t >> 6, lane = t & 63, quad = lane >> 4, ln = lane & 15;
  const int wm = (wave >> 1) * 64, wn = (wave & 1) * 64;
  const int m0 = blockIdx.y * 128, n0 = blockIdx.x * 128;
  const int nt = K >> 5;  // 32 K-tiles

  const int srow = lane >> 2;
  const int schunk = ((lane & 3) ^ ((lane >> 3) & 3)) * 8;
  const bf16_t* gA0 = &A[(size_t)(m0 + wave * 32 + srow) * K + schunk];
  const bf16_t* gA1 = gA0 + (size_t)16 * K;
  const bf16_t* gB0 = &B[(size_t)(n0 + wave * 32 + srow) * K + schunk];
  const bf16_t* gB1 = gB0 + (size_t)16 * K;

  const int cslot = (quad ^ ((ln >> 1) & 3)) * 8;

  f32x4 acc[4][4];
#pragma unroll
  for (int i = 0; i < 4; i++)
#pragma unroll
    for (int j = 0; j < 4; j++) acc[i][j] = (f32x4){0.f, 0.f, 0.f, 0.f};

  auto stage = [&](int tl) {
    const int buf = tl & 1;
    const int k0 = tl * 32;
    g2l16(gA0 + k0, &As[buf][(wave * 32) * 32]);
    g2l16(gA1 + k0, &As[buf][(wave * 32 + 16) * 32]);
    g2l16(gB0 + k0, &Bs[buf][(wave * 32) * 32]);
    g2l16(gB1 + k0, &Bs[buf][(wave * 32 + 16) * 32]);
  };

  // prologue: stage tile 0, drain, go.
  stage(0);
  __syncthreads();

  for (int tl = 0; tl < nt; ++tl) {
    const int buf = tl & 1;
    if (tl + 1 < nt) stage(tl + 1);  // HBM latency hides under this tile
    bf16x8 af[4], bfr[4];
#pragma unroll
    for (int mt = 0; mt < 4; mt++)
      af[mt] = *(const bf16x8*)&As[buf][(wm + mt * 16 + ln) * 32 + cslot];
#pragma unroll
    for (int nf = 0; nf < 4; nf++)
      bfr[nf] = *(const bf16x8*)&Bs[buf][(wn + nf * 16 + ln) * 32 + cslot];
#pragma unroll
    for (int mt = 0; mt < 4; mt++)
#pragma unroll
      for (int nf = 0; nf < 4; nf++)
        acc[mt][nf] = MFMA16(af[mt], bfr[nf], acc[mt][nf]);
    __syncthreads();  // vmcnt(0)+lgkmcnt(0)+barrier, once per tile
  }

#pragma unroll
  for (int nf = 0; nf < 4; nf++) {
    const int col = n0 + wn + nf * 16 + ln;
    const float bv = bias[col];
#pragma unroll
    for (int mt = 0; mt < 4; mt++) {
      const int row = m0 + wm + mt * 16 + quad * 4;
#pragma unroll
      for (int r = 0; r < 4; r++)
        C[(size_t)(row + r) * N + col] = (bf16_t)(acc[mt][nf][r] + bv);
    }
  }
}

// ---------------------------------------------------------------------------
// BM x 128 BT-GEMM, BK=64 double-buffer, ONE barrier per K-tile (R8/R10).
// Kept for GEMM2: BM=64, 48 KiB LDS, grid (1024/128)x(4096/64) = 512 blocks
// = exactly 2/CU (R5 lesson: co-residency >= 2). Swizzle verbatim from the
// refcheck-verified gemm256 lineage.
// ---------------------------------------------------------------------------
template <int BM, typename TC>
__launch_bounds__(256, 2)
__global__ void gemm128db(const bf16_t* __restrict__ A,
                          const bf16_t* __restrict__ B,
                          const float* __restrict__ bias,
                          TC* __restrict__ C,
                          int M, int N, int K) {
  constexpr int MF = BM / 32;  // m-frags per wave (BM/2 rows / 16)
  __shared__ __align__(16) bf16_t Ab[2][BM * 64];
  __shared__ __align__(16) bf16_t Bb[2][128 * 64];

  const int tid = threadIdx.x;
  const int wave = tid >> 6, lane = tid & 63, quad = lane >> 4, ln = lane & 15;
  const int wm = wave >> 1, wn = wave & 1;  // 2M x 2N
  const int m0 = blockIdx.y * BM, n0 = blockIdx.x * 128;
  const int nt = K >> 6;

  const int rowoff = wave * 8 + (lane >> 3);          // 0..31
  const int c8 = ((lane & 7) ^ (lane >> 3)) * 8;      // inverse-swizzled src
  const int w8row = wave * 8;
  const bf16_t* Arow0 = A + (size_t)(m0 + rowoff) * K + c8;
  const bf16_t* Brow0 = B + (size_t)(n0 + rowoff) * K + c8;

  auto stA = [&](int tl) {
    const bf16_t* g = Arow0 + (size_t)tl * 64;
    bf16_t* l = &Ab[tl & 1][w8row * 64];
#pragma unroll
    for (int rr = 0; rr < BM; rr += 32)
      g2l16(g + (size_t)rr * K, l + rr * 64);
  };
  auto stB = [&](int tl) {
    const bf16_t* g = Brow0 + (size_t)tl * 64;
    bf16_t* l = &Bb[tl & 1][w8row * 64];
#pragma unroll
    for (int rr = 0; rr < 128; rr += 32)
      g2l16(g + (size_t)rr * K, l + rr * 64);
  };

  const int cswl = (quad ^ (ln & 7)) * 8;
  const int aBase = (wm * (BM / 2) + ln) * 64;
  const int bBase = (wn * 64 + ln) * 64;

  f32x4 acc[MF][4];
#pragma unroll
  for (int i = 0; i < MF; i++)
#pragma unroll
    for (int j = 0; j < 4; j++) acc[i][j] = (f32x4){0.f, 0.f, 0.f, 0.f};

  bf16x8 af[MF][2], bfr[4][2];

  auto ldA = [&](int buf) {
#pragma unroll
    for (int mf = 0; mf < MF; ++mf)
#pragma unroll
      for (int sk = 0; sk < 2; ++sk)
        af[mf][sk] = *(const bf16x8*)&Ab[buf][aBase + mf * 1024 +
                                             (cswl ^ (sk << 5))];
  };
  auto ldB = [&](int buf) {
#pragma unroll
    for (int nf = 0; nf < 4; ++nf)
#pragma unroll
      for (int sk = 0; sk < 2; ++sk)
        bfr[nf][sk] = *(const bf16x8*)&Bb[buf][bBase + nf * 1024 +
                                               (cswl ^ (sk << 5))];
  };
  auto mm = [&]() {
#pragma unroll
    for (int mf = 0; mf < MF; ++mf)
#pragma unroll
      for (int nf = 0; nf < 4; ++nf) {
        f32x4 c = acc[mf][nf];
        c = MFMA16(af[mf][0], bfr[nf][0], c);
        c = MFMA16(af[mf][1], bfr[nf][1], c);
        acc[mf][nf] = c;
      }
  };

  stA(0); stB(0);
  __syncthreads();

  for (int tl = 0; tl < nt; ++tl) {
    const int buf = tl & 1;
    if (tl + 1 < nt) { stA(tl + 1); stB(tl + 1); }
    ldA(buf);
    ldB(buf);
    mm();
    __syncthreads();
  }

#pragma unroll
  for (int nf = 0; nf < 4; ++nf) {
    const int col = n0 + wn * 64 + nf * 16 + ln;
    const float bv = bias[col];
#pragma unroll
    for (int mf = 0; mf < MF; ++mf) {
      const int row = m0 + wm * (BM / 2) + mf * 16 + quad * 4;
#pragma unroll
      for (int r = 0; r < 4; ++r)
        C[(size_t)(row + r) * N + col] = (TC)(acc[mf][nf][r] + bv);
    }
  }
}

// ---------------------------------------------------------------------------
// Causal attention, K-SPLIT 8-WAVE, DIRECT-L2 K (R12).
// R9 structure kept: paired q-tiles (p,31-p), 512 blocks x 512 threads,
// wave w = (q-group w&3, k-half w>>2). NEW: K fragments are loaded DIRECTLY
// from global (L2-resident: 4 bh/XCD x 512KB = 2MB < 4MB L2 thanks to the
// R3 remap) — guide m169 lesson: staging L2-fit data through LDS is pure
// overhead. The K fragment is contiguous 16B in global: lane(ln,quad) needs
// K[row=kt*64+kh*32+sh*16+ln][quad*8..+7] (kf1: +32). Verified algebra: the
// old LDS roundtrip's read slot (quad+rot)&7 held logical chunk quad, so
// direct loads give bit-identical fragments. Removes per tile: 4
// ds_read_b128/wave, K LDS writes + K prefetch regs (K-waves). LDS drops
// 73728 -> 34816 B (V dbuf unioned with the reduction scratch).
// V staging unchanged (kh==0 waves, verified t&255 map). R6 f32x4 l-chains,
// T5 setprio, peeled causal phases kept. GRID MUST BE 512.
// ---------------------------------------------------------------------------
__launch_bounds__(512, 4)
__global__ void attn_kernel(const bf16_t* __restrict__ qkv,
                            bf16_t* __restrict__ out) {
  constexpr int VP = 72;
  constexpr int BUF = 64 * VP;  // 4608 elems per V buffer
  // union: V double-buffer (18432 B) | reduction scratch redA|redB (34816 B)
  __shared__ __align__(16) bf16_t smem[17408];
  bf16_t* VtB = smem;

  const int t = threadIdx.x;
  const int wave = t >> 6, lane = t & 63, quad = lane >> 4, ln = lane & 15;
  const int qw = wave & 3;   // q-row group (16 rows)
  const int kh = wave >> 2;  // k-half of each 64-row tile
  const int p = blockIdx.x >> 5;   // pair: q-tiles p and 31-p (0..15)
  const int bh = blockIdx.x & 31;  // same-bh -> same XCD (mod-8)
  const int b = bh >> 4, h = bh & 15;
  const int qA = p * 64, qB = (31 - p) * 64;
  const int ntiles = 32 - p;       // A active for kt <= p; B for all
  const size_t rs = 3072;
  const size_t base = (size_t)b * 2048 * rs;

  // Q as B-operand frags: B[d=quad*8+j][q=ln] = Q[q][d]  (dup across kh)
  const size_t qoffA = base + (size_t)(qA + qw * 16 + ln) * rs + h * 64;
  const size_t qoffB = base + (size_t)(qB + qw * 16 + ln) * rs + h * 64;
  bf16x8 qfA0 = *(const bf16x8*)&qkv[qoffA + quad * 8];
  bf16x8 qfA1 = *(const bf16x8*)&qkv[qoffA + 32 + quad * 8];
  bf16x8 qfB0 = *(const bf16x8*)&qkv[qoffB + quad * 8];
  bf16x8 qfB1 = *(const bf16x8*)&qkv[qoffB + 32 + quad * 8];

  // O^T accumulators (per k-half partial): rows d = ct*16+quad*4+r, col q=ln
  f32x4 oA[4], oB[4];
  f32x4 lAv = (f32x4){0.f, 0.f, 0.f, 0.f};
  f32x4 lBv = (f32x4){0.f, 0.f, 0.f, 0.f};
  for (int ct = 0; ct < 4; ct++) {
    oA[ct] = (f32x4){0.f, 0.f, 0.f, 0.f};
    oB[ct] = (f32x4){0.f, 0.f, 0.f, 0.f};
  }

  // direct-L2 K fragment pointer: row kh*32 + sh*16 + ln, chunk quad*8
  const bf16_t* kptr = &qkv[base + 1024 + h * 64 +
                            (size_t)(kh * 32 + ln) * rs + quad * 8];
  const size_t tstep = (size_t)64 * rs;

  // V staging (kh==0 waves only), verified 256-thread map
  const int t256 = t & 255;
  const int r0 = t256 >> 3, c0 = (t256 & 7) * 8;
  const int vkoff = ((((r0 >> 2) + (t256 & 7)) & 7)) * 8 + 2 * (r0 & 3);
  const bf16_t* vp0 = &qkv[base + 2048 + h * 64 + (size_t)(2 * r0) * rs + c0];
  const bf16_t* vp1 = vp0 + rs;
  bf16x8 s0, s1;
  if (!kh) {  // V tile 0 into regs
    s0 = *(const bf16x8*)vp0; vp0 += tstep;
    s1 = *(const bf16x8*)vp1; vp1 += tstep;
  }

  const int qgA = qA + qw * 16 + ln;  // lane's q (S^T column), set A
  const int qgB = qB + qw * 16 + ln;

  auto stage_to = [&](int buf) {  // call only under !kh
    bf16_t* VtW = &VtB[buf * BUF];
#pragma unroll
    for (int j = 0; j < 8; j++) {
      bf16x2 w2 = {s0[j], s1[j]};
      *(bf16x2*)&VtW[(c0 + j) * VP + vkoff] = w2;
    }
  };
  auto prefetchV = [&]() {
    s0 = *(const bf16x8*)vp0; vp0 += tstep;
    s1 = *(const bf16x8*)vp1; vp1 += tstep;
  };
  auto qk_block = [&](const bf16x8* k0, const bf16x8* k1, bf16x8 q0,
                      bf16x8 q1, f32x4& lxv, bf16x8& Bp, bool masked,
                      int kbase, int qg) {
    u32x4 u;
#pragma unroll
    for (int sh = 0; sh < 2; sh++) {
      f32x4 s = (f32x4){0.f, 0.f, 0.f, 0.f};
      __builtin_amdgcn_s_setprio(1);
      s = MFMA16(k0[sh], q0, s);
      s = MFMA16(k1[sh], q1, s);
      __builtin_amdgcn_s_setprio(0);
      const int k0g = kbase + (kh * 2 + sh) * 16 + quad * 4;
      float pv[4];
#pragma unroll
      for (int r = 0; r < 4; r++) {
        float e = __builtin_amdgcn_exp2f(fmaf(s[r], SCALE_L2E, ROUND_B));
        if (masked && (k0g + r > qg)) e = 0.f;
        lxv[r] += e;
        pv[r] = e;
      }
      u[sh * 2] = pack2(pv[0], pv[1]);
      u[sh * 2 + 1] = pack2(pv[2], pv[3]);
    }
    Bp = __builtin_bit_cast(bf16x8, u);
  };
  auto load_vfs = [&](const bf16_t* Vt, bf16x8* A8s) {
#pragma unroll
    for (int ct = 0; ct < 4; ct++) {
      const int dd = ct * 16 + ln;
      const int bc = (quad >> 1) + 2 * ct + (ln >> 3);
      const int cA = (4 * kh + bc) & 7;
      const int cB = (4 * kh + 2 + bc) & 7;
      bf16x4 v0 = *(const bf16x4*)&Vt[dd * VP + cA * 8 + (quad & 1) * 4];
      bf16x4 v1 = *(const bf16x4*)&Vt[dd * VP + cB * 8 + (quad & 1) * 4];
      A8s[ct] = __builtin_shufflevector(v0, v1, 0, 1, 2, 3, 4, 5, 6, 7);
    }
  };

  // main body for one k-tile. hasA/maskA/maskB are literals at call sites.
  auto body = [&](int kt, bool hasA, bool maskA, bool maskB) {
    // K frags for THIS tile, direct from L2 (issued first; the stage/address
    // work below plus 4-waves/SIMD TLP covers the ~200cy L2 latency)
    bf16x8 k0c[2], k1c[2];
    k0c[0] = *(const bf16x8*)kptr;
    k0c[1] = *(const bf16x8*)(kptr + 16 * rs);
    k1c[0] = *(const bf16x8*)(kptr + 32);
    k1c[1] = *(const bf16x8*)(kptr + 16 * rs + 32);
    kptr += tstep;
    if (!kh && kt + 1 < ntiles) {
      stage_to((kt + 1) & 1);
      if (kt + 2 < ntiles) prefetchV();
    }
    const bf16_t* Vt = &VtB[(kt & 1) * BUF];
    bf16x8 BpA, BpB;
    if (hasA) qk_block(k0c, k1c, qfA0, qfA1, lAv, BpA, maskA, kt * 64, qgA);
    qk_block(k0c, k1c, qfB0, qfB1, lBv, BpB, maskB, kt * 64, qgB);
    bf16x8 A8s[4];
    load_vfs(Vt, A8s);
    __builtin_amdgcn_s_setprio(1);
#pragma unroll
    for (int ct = 0; ct < 4; ct++) {
      if (hasA) oA[ct] = MFMA16(A8s[ct], BpA, oA[ct]);
      oB[ct] = MFMA16(A8s[ct], BpB, oB[ct]);
    }
    __builtin_amdgcn_s_setprio(0);
    if (kt + 1 < ntiles) __syncthreads();
  };

  // prologue: V tile 0 into buf0, prefetch V tile 1, sync (K needs none)
  if (!kh) {
    stage_to(0);
    if (ntiles > 1) prefetchV();
  }
  __syncthreads();

  // peeled phases: [0,p) AB | p A-diag | (p,31-p) B-only | 31-p B-diag
  for (int kt = 0; kt < p; kt++) body(kt, true, false, false);
  body(p, true, true, false);
  for (int kt = p + 1; kt < 31 - p; kt++) body(kt, false, false, false);
  body(31 - p, false, false, true);

  // per-wave l: fold f32x4 chains, sum across the 4 quads (k within half)
  float lAx = (lAv[0] + lAv[1]) + (lAv[2] + lAv[3]);
  float lBx = (lBv[0] + lBv[1]) + (lBv[2] + lBv[3]);
  lAx += __shfl_xor(lAx, 16);
  lAx += __shfl_xor(lAx, 32);
  lBx += __shfl_xor(lBx, 16);
  lBx += __shfl_xor(lBx, 32);

  // cross-half reduction via the (now dead) smem union. redA: bytes
  // [0,17408) = 4x256 f32x4 + 256 f32; redB: bytes [17408,34816).
  __syncthreads();  // all V reads complete before LDS reuse
  float* redA = (float*)smem;
  float* redB = (float*)(smem + 8704);  // 8704 bf16 = 17408 B
  const int idx = qw * 64 + lane;  // partner wave (qw, kh^1) has same idx
  if (kh) {
#pragma unroll
    for (int ct = 0; ct < 4; ct++) {
      *(f32x4*)&redA[(ct * 256 + idx) * 4] = oA[ct];
      *(f32x4*)&redB[(ct * 256 + idx) * 4] = oB[ct];
    }
    redA[4096 + idx] = lAx;
    redB[4096 + idx] = lBx;
  }
  __syncthreads();
  if (!kh) {
#pragma unroll
    for (int ct = 0; ct < 4; ct++) {
      oA[ct] += *(const f32x4*)&redA[(ct * 256 + idx) * 4];
      oB[ct] += *(const f32x4*)&redB[(ct * 256 + idx) * 4];
    }
    lAx += redA[4096 + idx];
    lBx += redB[4096 + idx];
    const float invA = __builtin_amdgcn_rcpf(lAx);
    const float invB = __builtin_amdgcn_rcpf(lBx);
    const int ocol = h * 64 + quad * 4;
#pragma unroll
    for (int ct = 0; ct < 4; ct++) {
      bf16x4 wa, wb;
#pragma unroll
      for (int r = 0; r < 4; r++) {
        wa[r] = (bf16_t)(oA[ct][r] * invA);
        wb[r] = (bf16_t)(oB[ct][r] * invB);
      }
      *(bf16x4*)&out[(size_t)(b * 2048 + qgA) * 1024 + ocol + ct * 16] = wa;
      *(bf16x4*)&out[(size_t)(b * 2048 + qgB) * 1024 + ocol + ct * 16] = wb;
    }
  }
}

extern "C" void kernel_launch(void* const* d_in, const int* in_sizes, int n_in,
                              void* d_out, int out_size, void* d_ws, size_t ws_size,
                              hipStream_t stream) {
  const float* x     = (const float*)d_in[0];  // [2,2048,1024]
  const float* w_qkv = (const float*)d_in[1];  // [3072,1024]
  const float* b_qkv = (const float*)d_in[2];  // [3072]
  const float* w_o   = (const float*)d_in[3];  // [1024,1024]
  const float* b_o   = (const float*)d_in[4];  // [1024]
  float* out = (float*)d_out;                  // [2,2048,1024]

  // workspace (bf16): qkv | xbf/attn (aliased) | wqkv_bf | wo_bf  = 42 MB
  bf16_t* qkv   = (bf16_t*)d_ws;
  bf16_t* xbf   = qkv + (size_t)4096 * 3072;
  bf16_t* wqkvb = xbf + (size_t)4096 * 1024;
  bf16_t* wob   = wqkvb + (size_t)3072 * 1024;
  bf16_t* attn  = xbf;  // x dead after GEMM1

  const int na = 4096 * 1024, nb = 3072 * 1024, nc = 1024 * 1024;
  convert3_f32_bf16<<<dim3((na + nb + nc) / (256 * 8)), 256, 0, stream>>>(
      x, na, w_qkv, nb, w_o, nc, xbf, wqkvb, wob);

  // 1) qkv = x @ w_qkv^T + b_qkv   (128^2 BK=32 dbuf 1-barrier, 768 blocks,
  //    4-5 blocks/CU co-resident)
  gemm128k32<<<dim3(3072 / 128, 4096 / 128), 256, 0, stream>>>(
      xbf, wqkvb, b_qkv, qkv, 4096, 3072, 1024);
  // 2) causal attention, paired q-tiles, k-split 8-wave, direct-L2 K:
  //    EXACTLY 512 blocks
  attn_kernel<<<dim3(512), 512, 0, stream>>>(qkv, attn);
  // 3) out = attn @ w_o^T + b_o    (64x128 dbuf 1-barrier, 512 blocks, 2/CU)
  gemm128db<64, float><<<dim3(1024 / 128, 4096 / 64), 256, 0, stream>>>(
      attn, wob, b_o, out, 4096, 1024, 1024);
}

// Round 13
// 166.583 us; speedup vs baseline: 1.1633x; 1.1633x over previous
//
#include <hip/hip_runtime.h>
#include <hip/hip_bf16.h>
#include <math.h>

typedef __bf16 bf16_t;
typedef __bf16 bf16x8 __attribute__((ext_vector_type(8)));
typedef __bf16 bf16x4 __attribute__((ext_vector_type(4)));
typedef __bf16 bf16x2 __attribute__((ext_vector_type(2)));
typedef float f32x4 __attribute__((ext_vector_type(4)));
typedef unsigned u32x4 __attribute__((ext_vector_type(4)));

// scale 1/sqrt(1024) folded with log2(e), plus half-ulp rounding bias
// (x * 2^0.0028169 = x * (1+2^-9)) so perm-truncation rounds on average.
#define SCALE_L2E 0.045084234f
#define ROUND_B 0.0028169f

#define MFMA16(a, b, c) __builtin_amdgcn_mfma_f32_16x16x32_bf16(a, b, c, 0, 0, 0)

// pack two f32 into bf16x2 (truncate): dst = (hi16(b) << 16) | hi16(a)
__device__ __forceinline__ unsigned pack2(float a, float b) {
  return __builtin_amdgcn_perm(__builtin_bit_cast(unsigned, b),
                               __builtin_bit_cast(unsigned, a), 0x07060302u);
}

// ---------------------------------------------------------------------------
// fused f32 -> bf16 convert of three buffers (x, w_qkv, w_o), 8 elems/thread
// ---------------------------------------------------------------------------
__global__ void convert3_f32_bf16(const float* __restrict__ a, int na,
                                  const float* __restrict__ b, int nb,
                                  const float* __restrict__ c, int nc,
                                  bf16_t* __restrict__ oa, bf16_t* __restrict__ ob,
                                  bf16_t* __restrict__ oc) {
  int i = (blockIdx.x * blockDim.x + threadIdx.x) * 8;
  const float* src;
  bf16_t* dst;
  int off;
  if (i < na) { src = a; dst = oa; off = i; }
  else if (i < na + nb) { src = b; dst = ob; off = i - na; }
  else if (i < na + nb + nc) { src = c; dst = oc; off = i - na - nb; }
  else return;
  float4 u = *(const float4*)&src[off];
  float4 v = *(const float4*)&src[off + 4];
  bf16x8 w = {(bf16_t)u.x, (bf16_t)u.y, (bf16_t)u.z, (bf16_t)u.w,
              (bf16_t)v.x, (bf16_t)v.y, (bf16_t)v.z, (bf16_t)v.w};
  *(bf16x8*)&dst[off] = w;
}

#define GLOBAL_AS __attribute__((address_space(1)))
#define LDS_AS __attribute__((address_space(3)))
__device__ __forceinline__ void g2l16(const void* g, void* l) {
  __builtin_amdgcn_global_load_lds((const GLOBAL_AS void*)g, (LDS_AS void*)l,
                                   16, 0, 0);
}

// ---------------------------------------------------------------------------
// 128x128 BT-GEMM, BK=32 double-buffer, ONE barrier per K-tile (R11, kept).
// 32 KiB LDS -> 4-5 blocks/CU co-resident; staging/read maps verbatim from
// the m97-style template that refcheck-passed R0-R4. R11 measured: total
// -3.5us vs the BK=64 2/CU variant (third confirmation that co-residency
// covers the per-tile vmcnt(0)+barrier drain).
// ---------------------------------------------------------------------------
__launch_bounds__(256, 4)
__global__ void gemm128k32(const bf16_t* __restrict__ A,
                           const bf16_t* __restrict__ B,
                           const float* __restrict__ bias,
                           bf16_t* __restrict__ C,
                           int M, int N, int K) {
  __shared__ __align__(16) bf16_t As[2][128 * 32];
  __shared__ __align__(16) bf16_t Bs[2][128 * 32];

  const int t = threadIdx.x;
  const int wave = t >> 6, lane = t & 63, quad = lane >> 4, ln = lane & 15;
  const int wm = (wave >> 1) * 64, wn = (wave & 1) * 64;
  const int m0 = blockIdx.y * 128, n0 = blockIdx.x * 128;
  const int nt = K >> 5;  // 32 K-tiles

  const int srow = lane >> 2;
  const int schunk = ((lane & 3) ^ ((lane >> 3) & 3)) * 8;
  const bf16_t* gA0 = &A[(size_t)(m0 + wave * 32 + srow) * K + schunk];
  const bf16_t* gA1 = gA0 + (size_t)16 * K;
  const bf16_t* gB0 = &B[(size_t)(n0 + wave * 32 + srow) * K + schunk];
  const bf16_t* gB1 = gB0 + (size_t)16 * K;

  const int cslot = (quad ^ ((ln >> 1) & 3)) * 8;

  f32x4 acc[4][4];
#pragma unroll
  for (int i = 0; i < 4; i++)
#pragma unroll
    for (int j = 0; j < 4; j++) acc[i][j] = (f32x4){0.f, 0.f, 0.f, 0.f};

  auto stage = [&](int tl) {
    const int buf = tl & 1;
    const int k0 = tl * 32;
    g2l16(gA0 + k0, &As[buf][(wave * 32) * 32]);
    g2l16(gA1 + k0, &As[buf][(wave * 32 + 16) * 32]);
    g2l16(gB0 + k0, &Bs[buf][(wave * 32) * 32]);
    g2l16(gB1 + k0, &Bs[buf][(wave * 32 + 16) * 32]);
  };

  // prologue: stage tile 0, drain, go.
  stage(0);
  __syncthreads();

  for (int tl = 0; tl < nt; ++tl) {
    const int buf = tl & 1;
    if (tl + 1 < nt) stage(tl + 1);  // HBM latency hides under this tile
    bf16x8 af[4], bfr[4];
#pragma unroll
    for (int mt = 0; mt < 4; mt++)
      af[mt] = *(const bf16x8*)&As[buf][(wm + mt * 16 + ln) * 32 + cslot];
#pragma unroll
    for (int nf = 0; nf < 4; nf++)
      bfr[nf] = *(const bf16x8*)&Bs[buf][(wn + nf * 16 + ln) * 32 + cslot];
#pragma unroll
    for (int mt = 0; mt < 4; mt++)
#pragma unroll
      for (int nf = 0; nf < 4; nf++)
        acc[mt][nf] = MFMA16(af[mt], bfr[nf], acc[mt][nf]);
    __syncthreads();  // vmcnt(0)+lgkmcnt(0)+barrier, once per tile
  }

#pragma unroll
  for (int nf = 0; nf < 4; nf++) {
    const int col = n0 + wn + nf * 16 + ln;
    const float bv = bias[col];
#pragma unroll
    for (int mt = 0; mt < 4; mt++) {
      const int row = m0 + wm + mt * 16 + quad * 4;
#pragma unroll
      for (int r = 0; r < 4; r++)
        C[(size_t)(row + r) * N + col] = (bf16_t)(acc[mt][nf][r] + bv);
    }
  }
}

// ---------------------------------------------------------------------------
// BM x 128 BT-GEMM, BK=64 double-buffer, ONE barrier per K-tile (R8/R10).
// Kept for GEMM2: BM=64, 48 KiB LDS, grid (1024/128)x(4096/64) = 512 blocks
// = exactly 2/CU (R5 lesson: co-residency >= 2). Swizzle verbatim from the
// refcheck-verified gemm256 lineage.
// ---------------------------------------------------------------------------
template <int BM, typename TC>
__launch_bounds__(256, 2)
__global__ void gemm128db(const bf16_t* __restrict__ A,
                          const bf16_t* __restrict__ B,
                          const float* __restrict__ bias,
                          TC* __restrict__ C,
                          int M, int N, int K) {
  constexpr int MF = BM / 32;  // m-frags per wave (BM/2 rows / 16)
  __shared__ __align__(16) bf16_t Ab[2][BM * 64];
  __shared__ __align__(16) bf16_t Bb[2][128 * 64];

  const int tid = threadIdx.x;
  const int wave = tid >> 6, lane = tid & 63, quad = lane >> 4, ln = lane & 15;
  const int wm = wave >> 1, wn = wave & 1;  // 2M x 2N
  const int m0 = blockIdx.y * BM, n0 = blockIdx.x * 128;
  const int nt = K >> 6;

  const int rowoff = wave * 8 + (lane >> 3);          // 0..31
  const int c8 = ((lane & 7) ^ (lane >> 3)) * 8;      // inverse-swizzled src
  const int w8row = wave * 8;
  const bf16_t* Arow0 = A + (size_t)(m0 + rowoff) * K + c8;
  const bf16_t* Brow0 = B + (size_t)(n0 + rowoff) * K + c8;

  auto stA = [&](int tl) {
    const bf16_t* g = Arow0 + (size_t)tl * 64;
    bf16_t* l = &Ab[tl & 1][w8row * 64];
#pragma unroll
    for (int rr = 0; rr < BM; rr += 32)
      g2l16(g + (size_t)rr * K, l + rr * 64);
  };
  auto stB = [&](int tl) {
    const bf16_t* g = Brow0 + (size_t)tl * 64;
    bf16_t* l = &Bb[tl & 1][w8row * 64];
#pragma unroll
    for (int rr = 0; rr < 128; rr += 32)
      g2l16(g + (size_t)rr * K, l + rr * 64);
  };

  const int cswl = (quad ^ (ln & 7)) * 8;
  const int aBase = (wm * (BM / 2) + ln) * 64;
  const int bBase = (wn * 64 + ln) * 64;

  f32x4 acc[MF][4];
#pragma unroll
  for (int i = 0; i < MF; i++)
#pragma unroll
    for (int j = 0; j < 4; j++) acc[i][j] = (f32x4){0.f, 0.f, 0.f, 0.f};

  bf16x8 af[MF][2], bfr[4][2];

  auto ldA = [&](int buf) {
#pragma unroll
    for (int mf = 0; mf < MF; ++mf)
#pragma unroll
      for (int sk = 0; sk < 2; ++sk)
        af[mf][sk] = *(const bf16x8*)&Ab[buf][aBase + mf * 1024 +
                                             (cswl ^ (sk << 5))];
  };
  auto ldB = [&](int buf) {
#pragma unroll
    for (int nf = 0; nf < 4; ++nf)
#pragma unroll
      for (int sk = 0; sk < 2; ++sk)
        bfr[nf][sk] = *(const bf16x8*)&Bb[buf][bBase + nf * 1024 +
                                               (cswl ^ (sk << 5))];
  };
  auto mm = [&]() {
#pragma unroll
    for (int mf = 0; mf < MF; ++mf)
#pragma unroll
      for (int nf = 0; nf < 4; ++nf) {
        f32x4 c = acc[mf][nf];
        c = MFMA16(af[mf][0], bfr[nf][0], c);
        c = MFMA16(af[mf][1], bfr[nf][1], c);
        acc[mf][nf] = c;
      }
  };

  stA(0); stB(0);
  __syncthreads();

  for (int tl = 0; tl < nt; ++tl) {
    const int buf = tl & 1;
    if (tl + 1 < nt) { stA(tl + 1); stB(tl + 1); }
    ldA(buf);
    ldB(buf);
    mm();
    __syncthreads();
  }

#pragma unroll
  for (int nf = 0; nf < 4; ++nf) {
    const int col = n0 + wn * 64 + nf * 16 + ln;
    const float bv = bias[col];
#pragma unroll
    for (int mf = 0; mf < MF; ++mf) {
      const int row = m0 + wm * (BM / 2) + mf * 16 + quad * 4;
#pragma unroll
      for (int r = 0; r < 4; ++r)
        C[(size_t)(row + r) * N + col] = (TC)(acc[mf][nf][r] + bv);
    }
  }
}

// ---------------------------------------------------------------------------
// Causal attention, K-SPLIT 8-WAVE (R9/R11, REVERTED to here after R12).
// R12's direct-L2 K regressed 40->66us: (1) 4x redundant K loads (each
// q-group wave re-read the same fragments the LDS path staged once), (2)
// uncoalesced 16B/lane reads spanning 32 cache lines/wave, (3) K load ->
// QK MFMA serial in-tile (~200cy L2 latency exposed; the LDS path hid it
// with one-tile-ahead register prefetch). m169's "don't stage L2-fit data"
// requires the direct consumer pattern to be coalesced + latency-tolerant —
// not true here. This version: paired q-tiles (p,31-p), 512 blocks x 512
// threads, wave w = (q-group w&3, k-half w>>2); K AND V staged through LDS
// by role (waves 0-3 V, waves 4-7 K, verified t&255 maps); cross-half O/l
// reduction through dead K/V LDS. R3 XCD map, R6 f32x4 l-chains kept.
// GRID MUST BE 512.
// ---------------------------------------------------------------------------
__launch_bounds__(512, 4)
__global__ void attn_kernel(const bf16_t* __restrict__ qkv,
                            bf16_t* __restrict__ out) {
  constexpr int KP = 72, VP = 72;
  constexpr int BUF = 64 * KP;  // elems per K (or V) buffer
  __shared__ __align__(16) bf16_t KsB[2 * BUF];  // [buf][k][d], swizzled
  __shared__ __align__(16) bf16_t VtB[2 * BUF];  // [buf][d][k], swizzled

  const int t = threadIdx.x;
  const int wave = t >> 6, lane = t & 63, quad = lane >> 4, ln = lane & 15;
  const int qw = wave & 3;   // q-row group (16 rows)
  const int kh = wave >> 2;  // k-half of each 64-row tile
  const int p = blockIdx.x >> 5;   // pair: q-tiles p and 31-p (0..15)
  const int bh = blockIdx.x & 31;  // same-bh -> same XCD (mod-8)
  const int b = bh >> 4, h = bh & 15;
  const int qA = p * 64, qB = (31 - p) * 64;
  const int ntiles = 32 - p;       // A active for kt <= p; B for all
  const size_t rs = 3072;
  const size_t base = (size_t)b * 2048 * rs;

  // Q as B-operand frags: B[d=quad*8+j][q=ln] = Q[q][d]  (dup across kh)
  const size_t qoffA = base + (size_t)(qA + qw * 16 + ln) * rs + h * 64;
  const size_t qoffB = base + (size_t)(qB + qw * 16 + ln) * rs + h * 64;
  bf16x8 qfA0 = *(const bf16x8*)&qkv[qoffA + quad * 8];
  bf16x8 qfA1 = *(const bf16x8*)&qkv[qoffA + 32 + quad * 8];
  bf16x8 qfB0 = *(const bf16x8*)&qkv[qoffB + quad * 8];
  bf16x8 qfB1 = *(const bf16x8*)&qkv[qoffB + 32 + quad * 8];

  // O^T accumulators (per k-half partial): rows d = ct*16+quad*4+r, col q=ln
  f32x4 oA[4], oB[4];
  f32x4 lAv = (f32x4){0.f, 0.f, 0.f, 0.f};
  f32x4 lBv = (f32x4){0.f, 0.f, 0.f, 0.f};
  for (int ct = 0; ct < 4; ct++) {
    oA[ct] = (f32x4){0.f, 0.f, 0.f, 0.f};
    oB[ct] = (f32x4){0.f, 0.f, 0.f, 0.f};
  }

  // staging: role split. kh=0 waves stage V, kh=1 waves stage K, each using
  // the verified 256-thread maps on t256 = t & 255.
  const int t256 = t & 255;
  const int r0 = t256 >> 3, c0 = (t256 & 7) * 8;
  const int wav4 = t256 >> 6;  // == r0>>3
  const int ksA = r0 * KP + (((t256 & 7) + wav4) & 7) * 8;
  const int ksB2 = (r0 + 32) * KP + (((t256 & 7) + wav4 + 4) & 7) * 8;
  const int vkoff = ((((r0 >> 2) + (t256 & 7)) & 7)) * 8 + 2 * (r0 & 3);

  const bf16_t* gp0;
  const bf16_t* gp1;
  if (kh) {  // K stager: rows r0, r0+32
    gp0 = &qkv[base + 1024 + h * 64 + (size_t)r0 * rs + c0];
    gp1 = gp0 + (size_t)32 * rs;
  } else {   // V stager: rows 2*r0, 2*r0+1
    gp0 = &qkv[base + 2048 + h * 64 + (size_t)(2 * r0) * rs + c0];
    gp1 = gp0 + rs;
  }
  const size_t tstep = (size_t)64 * rs;

  // tile 0 into regs (role-shared register pair)
  bf16x8 s0 = *(const bf16x8*)gp0; gp0 += tstep;
  bf16x8 s1 = *(const bf16x8*)gp1; gp1 += tstep;

  const int qgA = qA + qw * 16 + ln;  // lane's q (S^T column), set A
  const int qgB = qB + qw * 16 + ln;

  auto stage_to = [&](int buf) {
    if (kh) {
      bf16_t* KsW = &KsB[buf * BUF];
      *(bf16x8*)&KsW[ksA] = s0;
      *(bf16x8*)&KsW[ksB2] = s1;
    } else {
      bf16_t* VtW = &VtB[buf * BUF];
#pragma unroll
      for (int j = 0; j < 8; j++) {
        bf16x2 w2 = {s0[j], s1[j]};
        *(bf16x2*)&VtW[(c0 + j) * VP + vkoff] = w2;
      }
    }
  };
  auto prefetch = [&]() {
    s0 = *(const bf16x8*)gp0; gp0 += tstep;
    s1 = *(const bf16x8*)gp1; gp1 += tstep;
  };
  auto load_kfs = [&](const bf16_t* Ks, bf16x8* kf0s, bf16x8* kf1s) {
#pragma unroll
    for (int sh = 0; sh < 2; sh++) {
      const int st = kh * 2 + sh;
      const int krow = st * 16 + ln;
      const int rot = 2 * st + (ln >> 3);
      kf0s[sh] = *(const bf16x8*)&Ks[krow * KP + ((quad + rot) & 7) * 8];
      kf1s[sh] = *(const bf16x8*)&Ks[krow * KP + ((quad + 4 + rot) & 7) * 8];
    }
  };
  auto qk_block = [&](const bf16x8* kf0s, const bf16x8* kf1s, bf16x8 q0,
                      bf16x8 q1, f32x4& lxv, bf16x8& Bp, bool masked,
                      int kbase, int qg) {
    u32x4 u;
#pragma unroll
    for (int sh = 0; sh < 2; sh++) {
      f32x4 s = (f32x4){0.f, 0.f, 0.f, 0.f};
      __builtin_amdgcn_s_setprio(1);
      s = MFMA16(kf0s[sh], q0, s);
      s = MFMA16(kf1s[sh], q1, s);
      __builtin_amdgcn_s_setprio(0);
      const int k0g = kbase + (kh * 2 + sh) * 16 + quad * 4;
      float pv[4];
#pragma unroll
      for (int r = 0; r < 4; r++) {
        float e = __builtin_amdgcn_exp2f(fmaf(s[r], SCALE_L2E, ROUND_B));
        if (masked && (k0g + r > qg)) e = 0.f;
        lxv[r] += e;
        pv[r] = e;
      }
      u[sh * 2] = pack2(pv[0], pv[1]);
      u[sh * 2 + 1] = pack2(pv[2], pv[3]);
    }
    Bp = __builtin_bit_cast(bf16x8, u);
  };
  auto load_vfs = [&](const bf16_t* Vt, bf16x8* A8s) {
#pragma unroll
    for (int ct = 0; ct < 4; ct++) {
      const int dd = ct * 16 + ln;
      const int bc = (quad >> 1) + 2 * ct + (ln >> 3);
      const int cA = (4 * kh + bc) & 7;
      const int cB = (4 * kh + 2 + bc) & 7;
      bf16x4 v0 = *(const bf16x4*)&Vt[dd * VP + cA * 8 + (quad & 1) * 4];
      bf16x4 v1 = *(const bf16x4*)&Vt[dd * VP + cB * 8 + (quad & 1) * 4];
      A8s[ct] = __builtin_shufflevector(v0, v1, 0, 1, 2, 3, 4, 5, 6, 7);
    }
  };

  // main body for one k-tile. hasA/maskA/maskB are literals at call sites.
  auto body = [&](int kt, bool hasA, bool maskA, bool maskB) {
    if (kt + 1 < ntiles) {
      stage_to((kt + 1) & 1);
      if (kt + 2 < ntiles) prefetch();
    }
    const bf16_t* Ks = &KsB[(kt & 1) * BUF];
    const bf16_t* Vt = &VtB[(kt & 1) * BUF];
    bf16x8 kf0s[2], kf1s[2];
    load_kfs(Ks, kf0s, kf1s);
    bf16x8 BpA, BpB;
    if (hasA) qk_block(kf0s, kf1s, qfA0, qfA1, lAv, BpA, maskA, kt * 64, qgA);
    qk_block(kf0s, kf1s, qfB0, qfB1, lBv, BpB, maskB, kt * 64, qgB);
    bf16x8 A8s[4];
    load_vfs(Vt, A8s);
    __builtin_amdgcn_s_setprio(1);
#pragma unroll
    for (int ct = 0; ct < 4; ct++) {
      if (hasA) oA[ct] = MFMA16(A8s[ct], BpA, oA[ct]);
      oB[ct] = MFMA16(A8s[ct], BpB, oB[ct]);
    }
    __builtin_amdgcn_s_setprio(0);
    if (kt + 1 < ntiles) __syncthreads();
  };

  // prologue: tile 0 into buf0, prefetch tile 1, sync
  stage_to(0);
  if (ntiles > 1) prefetch();
  __syncthreads();

  // peeled phases: [0,p) AB | p A-diag | (p,31-p) B-only | 31-p B-diag
  for (int kt = 0; kt < p; kt++) body(kt, true, false, false);
  body(p, true, true, false);
  for (int kt = p + 1; kt < 31 - p; kt++) body(kt, false, false, false);
  body(31 - p, false, false, true);

  // per-wave l: fold f32x4 chains, sum across the 4 quads (k within half)
  float lAx = (lAv[0] + lAv[1]) + (lAv[2] + lAv[3]);
  float lBx = (lBv[0] + lBv[1]) + (lBv[2] + lBv[3]);
  lAx += __shfl_xor(lAx, 16);
  lAx += __shfl_xor(lAx, 32);
  lBx += __shfl_xor(lBx, 16);
  lBx += __shfl_xor(lBx, 32);

  // cross-half reduction via dead K/V LDS. Scratch: 4 ct x 256 idx f32x4
  // (16384 B) + 256 f32 l (1024 B) per buffer; KsB/VtB are 18432 B each.
  __syncthreads();  // all tile reads complete before LDS reuse
  float* redA = (float*)KsB;
  float* redB = (float*)VtB;
  const int idx = qw * 64 + lane;  // partner wave (qw, kh^1) has same idx
  if (kh) {
#pragma unroll
    for (int ct = 0; ct < 4; ct++) {
      *(f32x4*)&redA[(ct * 256 + idx) * 4] = oA[ct];
      *(f32x4*)&redB[(ct * 256 + idx) * 4] = oB[ct];
    }
    redA[4096 + idx] = lAx;
    redB[4096 + idx] = lBx;
  }
  __syncthreads();
  if (!kh) {
#pragma unroll
    for (int ct = 0; ct < 4; ct++) {
      oA[ct] += *(const f32x4*)&redA[(ct * 256 + idx) * 4];
      oB[ct] += *(const f32x4*)&redB[(ct * 256 + idx) * 4];
    }
    lAx += redA[4096 + idx];
    lBx += redB[4096 + idx];
    const float invA = __builtin_amdgcn_rcpf(lAx);
    const float invB = __builtin_amdgcn_rcpf(lBx);
    const int ocol = h * 64 + quad * 4;
#pragma unroll
    for (int ct = 0; ct < 4; ct++) {
      bf16x4 wa, wb;
#pragma unroll
      for (int r = 0; r < 4; r++) {
        wa[r] = (bf16_t)(oA[ct][r] * invA);
        wb[r] = (bf16_t)(oB[ct][r] * invB);
      }
      *(bf16x4*)&out[(size_t)(b * 2048 + qgA) * 1024 + ocol + ct * 16] = wa;
      *(bf16x4*)&out[(size_t)(b * 2048 + qgB) * 1024 + ocol + ct * 16] = wb;
    }
  }
}

extern "C" void kernel_launch(void* const* d_in, const int* in_sizes, int n_in,
                              void* d_out, int out_size, void* d_ws, size_t ws_size,
                              hipStream_t stream) {
  const float* x     = (const float*)d_in[0];  // [2,2048,1024]
  const float* w_qkv = (const float*)d_in[1];  // [3072,1024]
  const float* b_qkv = (const float*)d_in[2];  // [3072]
  const float* w_o   = (const float*)d_in[3];  // [1024,1024]
  const float* b_o   = (const float*)d_in[4];  // [1024]
  float* out = (float*)d_out;                  // [2,2048,1024]

  // workspace (bf16): qkv | xbf/attn (aliased) | wqkv_bf | wo_bf  = 42 MB
  bf16_t* qkv   = (bf16_t*)d_ws;
  bf16_t* xbf   = qkv + (size_t)4096 * 3072;
  bf16_t* wqkvb = xbf + (size_t)4096 * 1024;
  bf16_t* wob   = wqkvb + (size_t)3072 * 1024;
  bf16_t* attn  = xbf;  // x dead after GEMM1

  const int na = 4096 * 1024, nb = 3072 * 1024, nc = 1024 * 1024;
  convert3_f32_bf16<<<dim3((na + nb + nc) / (256 * 8)), 256, 0, stream>>>(
      x, na, w_qkv, nb, w_o, nc, xbf, wqkvb, wob);

  // 1) qkv = x @ w_qkv^T + b_qkv   (128^2 BK=32 dbuf 1-barrier, 768 blocks,
  //    4-5 blocks/CU co-resident)
  gemm128k32<<<dim3(3072 / 128, 4096 / 128), 256, 0, stream>>>(
      xbf, wqkvb, b_qkv, qkv, 4096, 3072, 1024);
  // 2) causal attention, paired q-tiles, k-split 8-wave: EXACTLY 512 blocks
  attn_kernel<<<dim3(512), 512, 0, stream>>>(qkv, attn);
  // 3) out = attn @ w_o^T + b_o    (64x128 dbuf 1-barrier, 512 blocks, 2/CU)
  gemm128db<64, float><<<dim3(1024 / 128, 4096 / 64), 256, 0, stream>>>(
      attn, wob, b_o, out, 4096, 1024, 1024);
}